// Round 1
// baseline (941.850 us; speedup 1.0000x reference)
//
#include <hip/hip_runtime.h>
#include <hip/hip_bf16.h>
#include <cstdint>

#define B_ 4
#define C_ 512
#define N_ 4096

typedef unsigned short u16;
typedef __bf16 bf16x8 __attribute__((ext_vector_type(8)));
typedef float f32x4 __attribute__((ext_vector_type(4)));

union U16B { uint4 u; bf16x8 v; };

__device__ __forceinline__ bf16x8 ld16g(const u16* p) {
  U16B t; t.u = *(const uint4*)p; return t.v;
}

__device__ __forceinline__ u16 f2bf(float f) {
  uint32_t u = __builtin_bit_cast(uint32_t, f);
  u = (u + 0x7FFFu + ((u >> 16) & 1u)) >> 16;
  return (u16)u;
}
__device__ __forceinline__ float bf2f(u16 h) {
  uint32_t u = ((uint32_t)h) << 16;
  return __builtin_bit_cast(float, u);
}

// ---------------- K0: f32 -> bf16 weight convert (512x512 each) -------------
__global__ __launch_bounds__(256) void cvt_w(const float* __restrict__ w, u16* __restrict__ o) {
  int i = blockIdx.x * 256 + threadIdx.x;          // 256 blocks * 256 thr * 4 = 262144
  float4 v = ((const float4*)w)[i];
  ushort4 r;
  r.x = f2bf(v.x); r.y = f2bf(v.y); r.z = f2bf(v.z); r.w = f2bf(v.w);
  ((ushort4*)o)[i] = r;
}

// ---------------- K1: instance-norm stats per (b,c) over 4096 ---------------
__global__ __launch_bounds__(256) void inorm_stats(const float* __restrict__ x,
    float* __restrict__ mu, float* __restrict__ rstd) {
  int bc = blockIdx.x;                              // 0..2047
  const float4* p = (const float4*)(x + (size_t)bc * N_);
  float s = 0.f, ss = 0.f;
  for (int i = threadIdx.x; i < N_ / 4; i += 256) {
    float4 v = p[i];
    s  += v.x + v.y + v.z + v.w;
    ss += v.x * v.x + v.y * v.y + v.z * v.z + v.w * v.w;
  }
#pragma unroll
  for (int off = 32; off > 0; off >>= 1) {
    s  += __shfl_down(s, off);
    ss += __shfl_down(ss, off);
  }
  __shared__ float as_[4], ass_[4];
  if ((threadIdx.x & 63) == 0) { as_[threadIdx.x >> 6] = s; ass_[threadIdx.x >> 6] = ss; }
  __syncthreads();
  if (threadIdx.x == 0) {
    float S  = as_[0] + as_[1] + as_[2] + as_[3];
    float SS = ass_[0] + ass_[1] + ass_[2] + ass_[3];
    float m  = S * (1.f / N_);
    float var = SS * (1.f / N_) - m * m;
    mu[bc] = m;
    rstd[bc] = rsqrtf(var + 1e-5f);
  }
}

// ---------------- K2: normalize + transpose -> hT (B,N,C) bf16 --------------
__global__ __launch_bounds__(256) void norm_transpose(const float* __restrict__ x,
    const float* __restrict__ mu, const float* __restrict__ rstd, u16* __restrict__ hT) {
  __shared__ u16 tile[64][66];                      // pad: row stride 132B == 1 bank shift
  int b = blockIdx.z, c0 = blockIdx.y * 64, n0 = blockIdx.x * 64;
  int tn = threadIdx.x & 63, t4 = threadIdx.x >> 6;
  const float* xb = x + ((size_t)b * C_ + c0) * N_ + n0;
#pragma unroll
  for (int it = 0; it < 16; ++it) {
    int c = t4 + it * 4;
    float m  = mu[b * C_ + c0 + c];
    float rs = rstd[b * C_ + c0 + c];
    tile[c][tn] = f2bf((xb[(size_t)c * N_ + tn] - m) * rs);
  }
  __syncthreads();
  u16* hTb = hT + ((size_t)b * N_ + n0) * C_ + c0;
#pragma unroll
  for (int it = 0; it < 16; ++it) {
    int n = t4 + it * 4;
    hTb[(size_t)n * C_ + tn] = tile[tn][n];
  }
}

// ---------------- K3: bf16 GEMM  out[m][n] = sum_k A[m][k]*B[n][k] (+bias) --
// A: M x 512 row-major bf16, Bm: Ncols x 512 row-major bf16. K = 512.
// bias_is_row=0: bias[col] (q/k proj), =1: bias[row] (v proj).
__global__ __launch_bounds__(256) void gemm_abT(
    const u16* __restrict__ A, const u16* __restrict__ Bm,
    const float* __restrict__ bias, u16* __restrict__ out,
    int ldo, int bias_is_row)
{
  int w = threadIdx.x >> 6, l = threadIdx.x & 63;
  int l16 = l & 15, lg = l >> 4;
  int m0 = blockIdx.x * 128 + (w >> 1) * 64;
  int n0 = blockIdx.y * 128 + (w & 1) * 64;
  f32x4 acc[4][4] = {};
  const u16* Ab = A  + (size_t)(m0 + l16) * 512 + lg * 8;
  const u16* Bb = Bm + (size_t)(n0 + l16) * 512 + lg * 8;
  for (int kc = 0; kc < 512; kc += 32) {
    bf16x8 af[4], bf[4];
#pragma unroll
    for (int i = 0; i < 4; ++i) af[i] = ld16g(Ab + (size_t)(i * 16) * 512 + kc);
#pragma unroll
    for (int j = 0; j < 4; ++j) bf[j] = ld16g(Bb + (size_t)(j * 16) * 512 + kc);
#pragma unroll
    for (int i = 0; i < 4; ++i)
#pragma unroll
      for (int j = 0; j < 4; ++j)
        acc[i][j] = __builtin_amdgcn_mfma_f32_16x16x32_bf16(af[i], bf[j], acc[i][j], 0, 0, 0);
  }
#pragma unroll
  for (int i = 0; i < 4; ++i) {
#pragma unroll
    for (int j = 0; j < 4; ++j) {
      int col = n0 + j * 16 + l16;
#pragma unroll
      for (int r = 0; r < 4; ++r) {
        int row = m0 + i * 16 + lg * 4 + r;
        float v = acc[i][j][r] + (bias_is_row ? bias[row] : bias[col]);
        out[(size_t)row * ldo + col] = f2bf(v);
      }
    }
  }
}

// ---------------- K4: fused attention  out = x + (P V^T)/rowsum(P) ----------
// qT,kT: (N,C) bf16; v: (C,N) bf16. Per block: 32 q-rows, 8 waves.
// No max-subtraction: |logit| < ~2 analytically, exp() is safe.
#define NQ 32
#define NKB 64
__global__ __launch_bounds__(512) void attn_kernel(
    const u16* __restrict__ qT, const u16* __restrict__ kT, const u16* __restrict__ vM,
    const float* __restrict__ x, float* __restrict__ out)
{
  int b = blockIdx.y;
  int nq0 = blockIdx.x * NQ;
  const u16* qTb = qT + (size_t)b * N_ * C_;
  const u16* kTb = kT + (size_t)b * N_ * C_;
  const u16* vb  = vM + (size_t)b * C_ * N_;
  const float* xb = x + (size_t)b * C_ * N_;
  float* ob = out + (size_t)b * C_ * N_;

  int tid = threadIdx.x;
  int w = tid >> 6, l = tid & 63, l16 = l & 15, lg = l >> 4;
  int nqf = w & 1, nkf = w >> 1;                    // S-frag owned by this wave
  int c0 = w * 64;                                  // PV output channel slice

  __shared__ u16 qlds[32][520];                     // 33280 B, stride 1040B (4-bank shift)
  __shared__ u16 Plds[32][72];                      // 4608 B, stride 144B
  __shared__ float dpart[32][16];
  __shared__ float dfin[32];

  // stage q tile (32 x 512 bf16)
  for (int idx = tid; idx < 32 * 64; idx += 512) {
    int row = idx >> 6, cg = idx & 63;
    *(uint4*)&qlds[row][cg * 8] = *(const uint4*)(qTb + (size_t)(nq0 + row) * C_ + cg * 8);
  }
  __syncthreads();

  f32x4 acc[2][4] = {};
  float dreg = 0.f;
  int drow = tid >> 4, dcol = (tid & 15) * 4;

  const float SCEXP = 0.06376149809794171f;         // 512^-0.5 * log2(e)

  for (int nk0 = 0; nk0 < N_; nk0 += NKB) {
    // ---- QK^T: this wave's 16x16 S fragment over K=512 ----
    f32x4 s = {0.f, 0.f, 0.f, 0.f};
    const u16* krow = kTb + (size_t)(nk0 + nkf * 16 + l16) * C_ + lg * 8;
#pragma unroll 4
    for (int kc = 0; kc < 16; ++kc) {
      U16B tq; tq.u = *(const uint4*)&qlds[nqf * 16 + l16][kc * 32 + lg * 8];
      bf16x8 kf = ld16g(krow + kc * 32);
      s = __builtin_amdgcn_mfma_f32_16x16x32_bf16(tq.v, kf, s, 0, 0, 0);
    }
    __syncthreads();                                // prev-iter P readers done
#pragma unroll
    for (int r = 0; r < 4; ++r) {
      float p = __builtin_amdgcn_exp2f(s[r] * SCEXP);
      Plds[nqf * 16 + lg * 4 + r][nkf * 16 + l16] = f2bf(p);
    }
    __syncthreads();
    // ---- denominator partials (consistent with bf16 P used in PV) ----
#pragma unroll
    for (int r = 0; r < 4; ++r) dreg += bf2f(Plds[drow][dcol + r]);
    // ---- PV: acc[nq-frag][c-frag] += P * V^T ----
#pragma unroll
    for (int kk = 0; kk < 2; ++kk) {
      bf16x8 pf[2];
#pragma unroll
      for (int i = 0; i < 2; ++i) {
        U16B t; t.u = *(const uint4*)&Plds[i * 16 + l16][kk * 32 + lg * 8];
        pf[i] = t.v;
      }
#pragma unroll
      for (int j = 0; j < 4; ++j) {
        bf16x8 vf = ld16g(vb + (size_t)(c0 + j * 16 + l16) * N_ + nk0 + kk * 32 + lg * 8);
#pragma unroll
        for (int i = 0; i < 2; ++i)
          acc[i][j] = __builtin_amdgcn_mfma_f32_16x16x32_bf16(pf[i], vf, acc[i][j], 0, 0, 0);
      }
    }
  }

  // ---- reduce denominators ----
  dpart[drow][tid & 15] = dreg;
  __syncthreads();
  if (tid < 32) {
    float s2 = 0.f;
#pragma unroll
    for (int g = 0; g < 16; ++g) s2 += dpart[tid][g];
    dfin[tid] = s2;
  }
  __syncthreads();

  // ---- epilogue: out[c][n] = x[c][n] + acc/denom ----
#pragma unroll
  for (int i = 0; i < 2; ++i) {
    float dinv[4];
#pragma unroll
    for (int r = 0; r < 4; ++r) dinv[r] = 1.f / dfin[i * 16 + lg * 4 + r];
    int nbase = nq0 + i * 16 + lg * 4;
#pragma unroll
    for (int j = 0; j < 4; ++j) {
      int c = c0 + j * 16 + l16;
      float4 xv = *(const float4*)(xb + (size_t)c * N_ + nbase);
      float4 o;
      o.x = xv.x + acc[i][j][0] * dinv[0];
      o.y = xv.y + acc[i][j][1] * dinv[1];
      o.z = xv.z + acc[i][j][2] * dinv[2];
      o.w = xv.w + acc[i][j][3] * dinv[3];
      *(float4*)(ob + (size_t)c * N_ + nbase) = o;
    }
  }
}

extern "C" void kernel_launch(void* const* d_in, const int* in_sizes, int n_in,
                              void* d_out, int out_size, void* d_ws, size_t ws_size,
                              hipStream_t stream) {
  (void)in_sizes; (void)n_in; (void)out_size; (void)ws_size;
  const float* x  = (const float*)d_in[0];
  const float* wq = (const float*)d_in[1];
  const float* bq = (const float*)d_in[2];
  const float* wk = (const float*)d_in[3];
  const float* bk = (const float*)d_in[4];
  const float* wv = (const float*)d_in[5];
  const float* bv = (const float*)d_in[6];
  float* out = (float*)d_out;
  char* ws = (char*)d_ws;

  // workspace layout (bytes)
  u16*   wbf_q = (u16*)(ws);                        //  0.5 MB
  u16*   wbf_k = (u16*)(ws + 524288);
  u16*   wbf_v = (u16*)(ws + 1048576);
  float* mu    = (float*)(ws + 1572864);            //  8 KB
  float* rstd  = (float*)(ws + 1581056);            //  8 KB
  u16*   hT    = (u16*)(ws + 1589248);              // 16 MB (B,N,C)
  u16*   qT    = (u16*)(ws + 18366464);             // 16 MB (B,N,C)
  u16*   kT    = (u16*)(ws + 35143680);             // 16 MB (B,N,C)
  u16*   vM    = (u16*)(ws + 51920896);             // 16 MB (B,C,N)  total ~65.5 MB

  cvt_w<<<256, 256, 0, stream>>>(wq, wbf_q);
  cvt_w<<<256, 256, 0, stream>>>(wk, wbf_k);
  cvt_w<<<256, 256, 0, stream>>>(wv, wbf_v);
  inorm_stats<<<B_ * C_, 256, 0, stream>>>(x, mu, rstd);
  norm_transpose<<<dim3(N_ / 64, C_ / 64, B_), 256, 0, stream>>>(x, mu, rstd, hT);

  for (int b = 0; b < B_; ++b) {
    const u16* hTb = hT + (size_t)b * N_ * C_;
    u16* qTb = qT + (size_t)b * N_ * C_;
    u16* kTb = kT + (size_t)b * N_ * C_;
    u16* vMb = vM + (size_t)b * C_ * N_;
    // qT[n][o] = sum_c hT[n][c] * wq[o][c] + bq[o]
    gemm_abT<<<dim3(N_ / 128, C_ / 128), 256, 0, stream>>>(hTb, wbf_q, bq, qTb, C_, 0);
    gemm_abT<<<dim3(N_ / 128, C_ / 128), 256, 0, stream>>>(hTb, wbf_k, bk, kTb, C_, 0);
    // v[o][n] = sum_c wv[o][c] * hT[n][c] + bv[o]
    gemm_abT<<<dim3(C_ / 128, N_ / 128), 256, 0, stream>>>(wbf_v, hTb, bv, vMb, N_, 1);
  }

  attn_kernel<<<dim3(N_ / NQ, B_), 512, 0, stream>>>(qT, kT, vM, x, out);
}

// Round 2
// 342.039 us; speedup vs baseline: 2.7536x; 2.7536x over previous
//
#include <hip/hip_runtime.h>
#include <hip/hip_bf16.h>
#include <cstdint>

#define B_ 4
#define C_ 512
#define N_ 4096

typedef unsigned short u16;
typedef __bf16 bf16x8 __attribute__((ext_vector_type(8)));
typedef float f32x4 __attribute__((ext_vector_type(4)));

union U16B { uint4 u; bf16x8 v; };

__device__ __forceinline__ bf16x8 ld16g(const u16* p) {
  U16B t; t.u = *(const uint4*)p; return t.v;
}

__device__ __forceinline__ u16 f2bf(float f) {
  uint32_t u = __builtin_bit_cast(uint32_t, f);
  u = (u + 0x7FFFu + ((u >> 16) & 1u)) >> 16;
  return (u16)u;
}
__device__ __forceinline__ float bf2f(u16 h) {
  uint32_t u = ((uint32_t)h) << 16;
  return __builtin_bit_cast(float, u);
}

typedef const __attribute__((address_space(1))) uint32_t* gas_p;
typedef __attribute__((address_space(3))) uint32_t* las_p;
__device__ __forceinline__ void gld16(const void* g, void* l) {
  __builtin_amdgcn_global_load_lds((gas_p)g, (las_p)l, 16, 0, 0);
}

// ---------------- K0: f32 -> bf16 weight convert (512x512 each) -------------
__global__ __launch_bounds__(256) void cvt_w(const float* __restrict__ w, u16* __restrict__ o) {
  int i = blockIdx.x * 256 + threadIdx.x;
  float4 v = ((const float4*)w)[i];
  ushort4 r;
  r.x = f2bf(v.x); r.y = f2bf(v.y); r.z = f2bf(v.z); r.w = f2bf(v.w);
  ((ushort4*)o)[i] = r;
}

// ---------------- K1: instance-norm stats per (b,c) over 4096 ---------------
__global__ __launch_bounds__(256) void inorm_stats(const float* __restrict__ x,
    float* __restrict__ mu, float* __restrict__ rstd) {
  int bc = blockIdx.x;
  const float4* p = (const float4*)(x + (size_t)bc * N_);
  float s = 0.f, ss = 0.f;
  for (int i = threadIdx.x; i < N_ / 4; i += 256) {
    float4 v = p[i];
    s  += v.x + v.y + v.z + v.w;
    ss += v.x * v.x + v.y * v.y + v.z * v.z + v.w * v.w;
  }
#pragma unroll
  for (int off = 32; off > 0; off >>= 1) {
    s  += __shfl_down(s, off);
    ss += __shfl_down(ss, off);
  }
  __shared__ float as_[4], ass_[4];
  if ((threadIdx.x & 63) == 0) { as_[threadIdx.x >> 6] = s; ass_[threadIdx.x >> 6] = ss; }
  __syncthreads();
  if (threadIdx.x == 0) {
    float S  = as_[0] + as_[1] + as_[2] + as_[3];
    float SS = ass_[0] + ass_[1] + ass_[2] + ass_[3];
    float m  = S * (1.f / N_);
    float var = SS * (1.f / N_) - m * m;
    mu[bc] = m;
    rstd[bc] = rsqrtf(var + 1e-5f);
  }
}

// ---------------- K2: normalize + transpose -> hT (B,N,C) bf16 --------------
__global__ __launch_bounds__(256) void norm_transpose(const float* __restrict__ x,
    const float* __restrict__ mu, const float* __restrict__ rstd, u16* __restrict__ hT) {
  __shared__ u16 tile[64][66];
  int b = blockIdx.z, c0 = blockIdx.y * 64, n0 = blockIdx.x * 64;
  int tn = threadIdx.x & 63, t4 = threadIdx.x >> 6;
  const float* xb = x + ((size_t)b * C_ + c0) * N_ + n0;
#pragma unroll
  for (int it = 0; it < 16; ++it) {
    int c = t4 + it * 4;
    float m  = mu[b * C_ + c0 + c];
    float rs = rstd[b * C_ + c0 + c];
    tile[c][tn] = f2bf((xb[(size_t)c * N_ + tn] - m) * rs);
  }
  __syncthreads();
  u16* hTb = hT + ((size_t)b * N_ + n0) * C_ + c0;
#pragma unroll
  for (int it = 0; it < 16; ++it) {
    int n = t4 + it * 4;
    hTb[(size_t)n * C_ + tn] = tile[tn][n];
  }
}

// ============== NEW: 128x128 bf16 GEMM core (BK=64, dbuf, swizzled) =========
// D[m][n] = sum_k A[m][k] * B[n][k], A/B row-major k-contiguous bf16.
// EPI: 0 = proj bias[col] -> bf16, 1 = proj bias[row] -> bf16,
//      2 = P = exp2(acc*SCEXP) -> bf16 + rowsum atomics to dsum,
//      3 = atomicAdd(out, acc / aux[col]) (f32 out pre-inited to x).
#define EPI_BCOL 0
#define EPI_BROW 1
#define EPI_EXP  2
#define EPI_PV   3

#define SCEXP 0.06376149809794171f  /* 512^-0.5 * log2(e) */

template<int EPI>
__global__ __launch_bounds__(256) void gemm128(
    const u16* __restrict__ A, const u16* __restrict__ B,
    const float* __restrict__ aux, float* __restrict__ dsum,
    void* __restrict__ Out,
    int klen, int lda, int ldb, int ldo,
    long sAz, long sBz, long sOz, int koffZ)
{
  int z = blockIdx.z;
  const u16* Ab = A + (size_t)z * sAz;
  const u16* Bb = B + (size_t)z * sBz;
  int k0 = z * koffZ;
  int m0 = blockIdx.x * 128, n0 = blockIdx.y * 128;
  int t = threadIdx.x, w = t >> 6, l = t & 63;
  int wr = w >> 1, wc = w & 1;
  int l16 = l & 15, lg = l >> 4;

  __shared__ char smem[65536];            // 2 x (A 16KB + B 16KB)

  // staging address constants (XOR-swizzled source, linear LDS dest)
  int srow = t >> 3;                       // + i*32
  int scol = ((t & 7) << 4) ^ ((srow & 7) << 4);
  size_t ldaB = (size_t)lda * 2, ldbB = (size_t)ldb * 2;

  f32x4 acc[4][4] = {};
  int nsteps = klen >> 6;

#define STAGE(step, d) {                                                     \
    size_t kbyte = (size_t)(k0 + (step) * 64) * 2 + scol;                    \
    char* lb = smem + (d) * 32768;                                           \
    _Pragma("unroll")                                                        \
    for (int i = 0; i < 4; ++i) {                                            \
      int row = i * 32 + srow;                                               \
      gld16((const char*)Ab + (size_t)(m0 + row) * ldaB + kbyte,             \
            lb + (size_t)(i * 256 + t) * 16);                                \
      gld16((const char*)Bb + (size_t)(n0 + row) * ldbB + kbyte,             \
            lb + 16384 + (size_t)(i * 256 + t) * 16);                        \
    }                                                                        \
  }

  STAGE(0, 0);
  __syncthreads();
  int cur = 0;
  int sw = (l16 & 7) << 4;
  for (int s = 0; s < nsteps; ++s) {
    if (s + 1 < nsteps) STAGE(s + 1, cur ^ 1);
    const char* Al = smem + cur * 32768;
    const char* Bl = Al + 16384;
#pragma unroll
    for (int kc = 0; kc < 2; ++kc) {
      int cb = (kc * 64 + lg * 16) ^ sw;
      bf16x8 af[4], bf[4];
#pragma unroll
      for (int mf = 0; mf < 4; ++mf)
        af[mf] = *(const bf16x8*)(Al + (wr * 64 + mf * 16 + l16) * 128 + cb);
#pragma unroll
      for (int nf = 0; nf < 4; ++nf)
        bf[nf] = *(const bf16x8*)(Bl + (wc * 64 + nf * 16 + l16) * 128 + cb);
#pragma unroll
      for (int mf = 0; mf < 4; ++mf)
#pragma unroll
        for (int nf = 0; nf < 4; ++nf)
          acc[mf][nf] = __builtin_amdgcn_mfma_f32_16x16x32_bf16(af[mf], bf[nf], acc[mf][nf], 0, 0, 0);
    }
    __syncthreads();
    cur ^= 1;
  }
#undef STAGE

  // ---- epilogues ----
  if constexpr (EPI == EPI_BCOL || EPI == EPI_BROW) {
    u16* ob = (u16*)Out + (size_t)z * sOz;
    float bc[4];
    if constexpr (EPI == EPI_BCOL) {
#pragma unroll
      for (int nf = 0; nf < 4; ++nf) bc[nf] = aux[n0 + wc * 64 + nf * 16 + l16];
    }
#pragma unroll
    for (int mf = 0; mf < 4; ++mf) {
#pragma unroll
      for (int nf = 0; nf < 4; ++nf) {
        int col = n0 + wc * 64 + nf * 16 + l16;
#pragma unroll
        for (int r = 0; r < 4; ++r) {
          int row = m0 + wr * 64 + mf * 16 + lg * 4 + r;
          float v = acc[mf][nf][r] + (EPI == EPI_BCOL ? bc[nf] : aux[row]);
          ob[(size_t)row * ldo + col] = f2bf(v);
        }
      }
    }
  } else if constexpr (EPI == EPI_EXP) {
    u16* ob = (u16*)Out;
#pragma unroll
    for (int mf = 0; mf < 4; ++mf) {
#pragma unroll
      for (int r = 0; r < 4; ++r) {
        int row = m0 + wr * 64 + mf * 16 + lg * 4 + r;
        float rs = 0.f;
#pragma unroll
        for (int nf = 0; nf < 4; ++nf) {
          int col = n0 + wc * 64 + nf * 16 + l16;
          float p = __builtin_amdgcn_exp2f(acc[mf][nf][r] * SCEXP);
          u16 pb = f2bf(p);
          ob[(size_t)row * ldo + col] = pb;
          rs += bf2f(pb);
        }
        rs += __shfl_xor(rs, 1); rs += __shfl_xor(rs, 2);
        rs += __shfl_xor(rs, 4); rs += __shfl_xor(rs, 8);
        if (l16 == 0) atomicAdd(&dsum[row], rs);
      }
    }
  } else {  // EPI_PV
    float* ob = (float*)Out;
    float rd[4];
#pragma unroll
    for (int nf = 0; nf < 4; ++nf) rd[nf] = 1.0f / aux[n0 + wc * 64 + nf * 16 + l16];
#pragma unroll
    for (int mf = 0; mf < 4; ++mf) {
#pragma unroll
      for (int nf = 0; nf < 4; ++nf) {
        int col = n0 + wc * 64 + nf * 16 + l16;
#pragma unroll
        for (int r = 0; r < 4; ++r) {
          int row = m0 + wr * 64 + mf * 16 + lg * 4 + r;
          atomicAdd(&ob[(size_t)row * ldo + col], acc[mf][nf][r] * rd[nf]);
        }
      }
    }
  }
}

// ================== OLD PATH (round-1, fallback if ws too small) ============
__global__ __launch_bounds__(256) void gemm_abT(
    const u16* __restrict__ A, const u16* __restrict__ Bm,
    const float* __restrict__ bias, u16* __restrict__ out,
    int ldo, int bias_is_row)
{
  int w = threadIdx.x >> 6, l = threadIdx.x & 63;
  int l16 = l & 15, lg = l >> 4;
  int m0 = blockIdx.x * 128 + (w >> 1) * 64;
  int n0 = blockIdx.y * 128 + (w & 1) * 64;
  f32x4 acc[4][4] = {};
  const u16* Ab = A  + (size_t)(m0 + l16) * 512 + lg * 8;
  const u16* Bb = Bm + (size_t)(n0 + l16) * 512 + lg * 8;
  for (int kc = 0; kc < 512; kc += 32) {
    bf16x8 af[4], bf[4];
#pragma unroll
    for (int i = 0; i < 4; ++i) af[i] = ld16g(Ab + (size_t)(i * 16) * 512 + kc);
#pragma unroll
    for (int j = 0; j < 4; ++j) bf[j] = ld16g(Bb + (size_t)(j * 16) * 512 + kc);
#pragma unroll
    for (int i = 0; i < 4; ++i)
#pragma unroll
      for (int j = 0; j < 4; ++j)
        acc[i][j] = __builtin_amdgcn_mfma_f32_16x16x32_bf16(af[i], bf[j], acc[i][j], 0, 0, 0);
  }
#pragma unroll
  for (int i = 0; i < 4; ++i) {
#pragma unroll
    for (int j = 0; j < 4; ++j) {
      int col = n0 + j * 16 + l16;
#pragma unroll
      for (int r = 0; r < 4; ++r) {
        int row = m0 + i * 16 + lg * 4 + r;
        float v = acc[i][j][r] + (bias_is_row ? bias[row] : bias[col]);
        out[(size_t)row * ldo + col] = f2bf(v);
      }
    }
  }
}

#define NQ 32
#define NKB 64
__global__ __launch_bounds__(512) void attn_kernel(
    const u16* __restrict__ qT, const u16* __restrict__ kT, const u16* __restrict__ vM,
    const float* __restrict__ x, float* __restrict__ out)
{
  int b = blockIdx.y;
  int nq0 = blockIdx.x * NQ;
  const u16* qTb = qT + (size_t)b * N_ * C_;
  const u16* kTb = kT + (size_t)b * N_ * C_;
  const u16* vb  = vM + (size_t)b * C_ * N_;
  const float* xb = x + (size_t)b * C_ * N_;
  float* ob = out + (size_t)b * C_ * N_;

  int tid = threadIdx.x;
  int w = tid >> 6, l = tid & 63, l16 = l & 15, lg = l >> 4;
  int nqf = w & 1, nkf = w >> 1;
  int c0 = w * 64;

  __shared__ u16 qlds[32][520];
  __shared__ u16 Plds[32][72];
  __shared__ float dpart[32][16];
  __shared__ float dfin[32];

  for (int idx = tid; idx < 32 * 64; idx += 512) {
    int row = idx >> 6, cg = idx & 63;
    *(uint4*)&qlds[row][cg * 8] = *(const uint4*)(qTb + (size_t)(nq0 + row) * C_ + cg * 8);
  }
  __syncthreads();

  f32x4 acc[2][4] = {};
  float dreg = 0.f;
  int drow = tid >> 4, dcol = (tid & 15) * 4;

  for (int nk0 = 0; nk0 < N_; nk0 += NKB) {
    f32x4 s = {0.f, 0.f, 0.f, 0.f};
    const u16* krow = kTb + (size_t)(nk0 + nkf * 16 + l16) * C_ + lg * 8;
#pragma unroll 4
    for (int kc = 0; kc < 16; ++kc) {
      U16B tq; tq.u = *(const uint4*)&qlds[nqf * 16 + l16][kc * 32 + lg * 8];
      bf16x8 kf = ld16g(krow + kc * 32);
      s = __builtin_amdgcn_mfma_f32_16x16x32_bf16(tq.v, kf, s, 0, 0, 0);
    }
    __syncthreads();
#pragma unroll
    for (int r = 0; r < 4; ++r) {
      float p = __builtin_amdgcn_exp2f(s[r] * SCEXP);
      Plds[nqf * 16 + lg * 4 + r][nkf * 16 + l16] = f2bf(p);
    }
    __syncthreads();
#pragma unroll
    for (int r = 0; r < 4; ++r) dreg += bf2f(Plds[drow][dcol + r]);
#pragma unroll
    for (int kk = 0; kk < 2; ++kk) {
      bf16x8 pf[2];
#pragma unroll
      for (int i = 0; i < 2; ++i) {
        U16B t2; t2.u = *(const uint4*)&Plds[i * 16 + l16][kk * 32 + lg * 8];
        pf[i] = t2.v;
      }
#pragma unroll
      for (int j = 0; j < 4; ++j) {
        bf16x8 vf = ld16g(vb + (size_t)(c0 + j * 16 + l16) * N_ + nk0 + kk * 32 + lg * 8);
#pragma unroll
        for (int i = 0; i < 2; ++i)
          acc[i][j] = __builtin_amdgcn_mfma_f32_16x16x32_bf16(pf[i], vf, acc[i][j], 0, 0, 0);
      }
    }
  }

  dpart[drow][tid & 15] = dreg;
  __syncthreads();
  if (tid < 32) {
    float s2 = 0.f;
#pragma unroll
    for (int g = 0; g < 16; ++g) s2 += dpart[tid][g];
    dfin[tid] = s2;
  }
  __syncthreads();

#pragma unroll
  for (int i = 0; i < 2; ++i) {
    float dinv[4];
#pragma unroll
    for (int r = 0; r < 4; ++r) dinv[r] = 1.f / dfin[i * 16 + lg * 4 + r];
    int nbase = nq0 + i * 16 + lg * 4;
#pragma unroll
    for (int j = 0; j < 4; ++j) {
      int c = c0 + j * 16 + l16;
      float4 xv = *(const float4*)(xb + (size_t)c * N_ + nbase);
      float4 o;
      o.x = xv.x + acc[i][j][0] * dinv[0];
      o.y = xv.y + acc[i][j][1] * dinv[1];
      o.z = xv.z + acc[i][j][2] * dinv[2];
      o.w = xv.w + acc[i][j][3] * dinv[3];
      *(float4*)(ob + (size_t)c * N_ + nbase) = o;
    }
  }
}

extern "C" void kernel_launch(void* const* d_in, const int* in_sizes, int n_in,
                              void* d_out, int out_size, void* d_ws, size_t ws_size,
                              hipStream_t stream) {
  (void)in_sizes; (void)n_in; (void)out_size;
  const float* x  = (const float*)d_in[0];
  const float* wq = (const float*)d_in[1];
  const float* bq = (const float*)d_in[2];
  const float* wk = (const float*)d_in[3];
  const float* bk = (const float*)d_in[4];
  const float* wv = (const float*)d_in[5];
  const float* bv = (const float*)d_in[6];
  float* out = (float*)d_out;
  char* ws = (char*)d_ws;

  const size_t NC = (size_t)N_ * C_;     // 2097152
  const size_t NEED = 83902464;

  if (ws_size >= NEED) {
    // ---- new path: materialized-P two-GEMM attention ----
    // region [0, 33.55MB): phase-1 {wbf,stats,hT}, phase-2 P
    u16*   P     = (u16*)(ws);
    u16*   wbf_q = (u16*)(ws);
    u16*   wbf_k = (u16*)(ws + 524288);
    u16*   wbf_v = (u16*)(ws + 1048576);
    float* mu    = (float*)(ws + 1572864);
    float* rstd  = (float*)(ws + 1581056);
    u16*   hT    = (u16*)(ws + 1589248);
    u16*   qT    = (u16*)(ws + 33554432);
    u16*   kT    = (u16*)(ws + 50331648);
    u16*   vM    = (u16*)(ws + 67108864);
    float* denom = (float*)(ws + 83886080);

    cvt_w<<<256, 256, 0, stream>>>(wq, wbf_q);
    cvt_w<<<256, 256, 0, stream>>>(wk, wbf_k);
    cvt_w<<<256, 256, 0, stream>>>(wv, wbf_v);
    inorm_stats<<<B_ * C_, 256, 0, stream>>>(x, mu, rstd);
    norm_transpose<<<dim3(N_ / 64, C_ / 64, B_), 256, 0, stream>>>(x, mu, rstd, hT);

    // out = x (residual base for PV atomics)
    hipMemcpyAsync(out, x, (size_t)B_ * C_ * N_ * 4, hipMemcpyDeviceToDevice, stream);

    // projections, all batches per dispatch (z = batch)
    gemm128<EPI_BCOL><<<dim3(32, 4, 4), 256, 0, stream>>>(
        hT, wbf_q, bq, nullptr, qT, 512, 512, 512, 512, (long)NC, 0, (long)NC, 0);
    gemm128<EPI_BCOL><<<dim3(32, 4, 4), 256, 0, stream>>>(
        hT, wbf_k, bk, nullptr, kT, 512, 512, 512, 512, (long)NC, 0, (long)NC, 0);
    gemm128<EPI_BROW><<<dim3(4, 32, 4), 256, 0, stream>>>(
        wbf_v, hT, bv, nullptr, vM, 512, 512, 512, 4096, 0, (long)NC, (long)NC, 0);

    for (int b = 0; b < B_; ++b) {
      hipMemsetAsync(denom, 0, N_ * sizeof(float), stream);
      // P = exp2(scale * qT kT^T), rowsums -> denom
      gemm128<EPI_EXP><<<dim3(32, 32, 1), 256, 0, stream>>>(
          qT + (size_t)b * NC, kT + (size_t)b * NC, nullptr, denom, P,
          512, 512, 512, 4096, 0, 0, 0, 0);
      // out += vM P^T / denom   (z = K-split of 4096 into 2x2048)
      gemm128<EPI_PV><<<dim3(4, 32, 2), 256, 0, stream>>>(
          vM + (size_t)b * NC, P, denom, nullptr, out + (size_t)b * NC,
          2048, 4096, 4096, 4096, 0, 0, 0, 2048);
    }
  } else {
    // ---- fallback: round-1 path (65.5 MB ws) ----
    u16*   wbf_q = (u16*)(ws);
    u16*   wbf_k = (u16*)(ws + 524288);
    u16*   wbf_v = (u16*)(ws + 1048576);
    float* mu    = (float*)(ws + 1572864);
    float* rstd  = (float*)(ws + 1581056);
    u16*   hT    = (u16*)(ws + 1589248);
    u16*   qT    = (u16*)(ws + 18366464);
    u16*   kT    = (u16*)(ws + 35143680);
    u16*   vM    = (u16*)(ws + 51920896);

    cvt_w<<<256, 256, 0, stream>>>(wq, wbf_q);
    cvt_w<<<256, 256, 0, stream>>>(wk, wbf_k);
    cvt_w<<<256, 256, 0, stream>>>(wv, wbf_v);
    inorm_stats<<<B_ * C_, 256, 0, stream>>>(x, mu, rstd);
    norm_transpose<<<dim3(N_ / 64, C_ / 64, B_), 256, 0, stream>>>(x, mu, rstd, hT);

    for (int b = 0; b < B_; ++b) {
      const u16* hTb = hT + (size_t)b * NC;
      u16* qTb = qT + (size_t)b * NC;
      u16* kTb = kT + (size_t)b * NC;
      u16* vMb = vM + (size_t)b * NC;
      gemm_abT<<<dim3(N_ / 128, C_ / 128), 256, 0, stream>>>(hTb, wbf_q, bq, qTb, C_, 0);
      gemm_abT<<<dim3(N_ / 128, C_ / 128), 256, 0, stream>>>(hTb, wbf_k, bk, kTb, C_, 0);
      gemm_abT<<<dim3(C_ / 128, N_ / 128), 256, 0, stream>>>(wbf_v, hTb, bv, vMb, N_, 1);
    }
    attn_kernel<<<dim3(N_ / NQ, B_), 512, 0, stream>>>(qT, kT, vM, x, out);
  }
}

// Round 3
// 272.577 us; speedup vs baseline: 3.4554x; 1.2548x over previous
//
#include <hip/hip_runtime.h>
#include <hip/hip_bf16.h>
#include <cstdint>

#define B_ 4
#define C_ 512
#define N_ 4096

typedef unsigned short u16;
typedef __bf16 bf16x8 __attribute__((ext_vector_type(8)));
typedef float f32x4 __attribute__((ext_vector_type(4)));

union U16B { uint4 u; bf16x8 v; };

__device__ __forceinline__ bf16x8 ld16g(const u16* p) {
  U16B t; t.u = *(const uint4*)p; return t.v;
}

__device__ __forceinline__ u16 f2bf(float f) {
  uint32_t u = __builtin_bit_cast(uint32_t, f);
  u = (u + 0x7FFFu + ((u >> 16) & 1u)) >> 16;
  return (u16)u;
}
__device__ __forceinline__ float bf2f(u16 h) {
  uint32_t u = ((uint32_t)h) << 16;
  return __builtin_bit_cast(float, u);
}

typedef const __attribute__((address_space(1))) uint32_t* gas_p;
typedef __attribute__((address_space(3))) uint32_t* las_p;
__device__ __forceinline__ void gld16(const void* g, void* l) {
  __builtin_amdgcn_global_load_lds((gas_p)g, (las_p)l, 16, 0, 0);
}

// ---------------- K0: f32 -> bf16 weight convert (512x512 each) -------------
__global__ __launch_bounds__(256) void cvt_w(const float* __restrict__ w, u16* __restrict__ o) {
  int i = blockIdx.x * 256 + threadIdx.x;
  float4 v = ((const float4*)w)[i];
  ushort4 r;
  r.x = f2bf(v.x); r.y = f2bf(v.y); r.z = f2bf(v.z); r.w = f2bf(v.w);
  ((ushort4*)o)[i] = r;
}

// ---------------- K1: instance-norm stats per (b,c) over 4096 ---------------
__global__ __launch_bounds__(256) void inorm_stats(const float* __restrict__ x,
    float* __restrict__ mu, float* __restrict__ rstd) {
  int bc = blockIdx.x;
  const float4* p = (const float4*)(x + (size_t)bc * N_);
  float s = 0.f, ss = 0.f;
  for (int i = threadIdx.x; i < N_ / 4; i += 256) {
    float4 v = p[i];
    s  += v.x + v.y + v.z + v.w;
    ss += v.x * v.x + v.y * v.y + v.z * v.z + v.w * v.w;
  }
#pragma unroll
  for (int off = 32; off > 0; off >>= 1) {
    s  += __shfl_down(s, off);
    ss += __shfl_down(ss, off);
  }
  __shared__ float as_[4], ass_[4];
  if ((threadIdx.x & 63) == 0) { as_[threadIdx.x >> 6] = s; ass_[threadIdx.x >> 6] = ss; }
  __syncthreads();
  if (threadIdx.x == 0) {
    float S  = as_[0] + as_[1] + as_[2] + as_[3];
    float SS = ass_[0] + ass_[1] + ass_[2] + ass_[3];
    float m  = S * (1.f / N_);
    float var = SS * (1.f / N_) - m * m;
    mu[bc] = m;
    rstd[bc] = rsqrtf(var + 1e-5f);
  }
}

// ---------------- K2: normalize + transpose -> hT (B,N,C) bf16 --------------
__global__ __launch_bounds__(256) void norm_transpose(const float* __restrict__ x,
    const float* __restrict__ mu, const float* __restrict__ rstd, u16* __restrict__ hT) {
  __shared__ u16 tile[64][66];
  int b = blockIdx.z, c0 = blockIdx.y * 64, n0 = blockIdx.x * 64;
  int tn = threadIdx.x & 63, t4 = threadIdx.x >> 6;
  const float* xb = x + ((size_t)b * C_ + c0) * N_ + n0;
#pragma unroll
  for (int it = 0; it < 16; ++it) {
    int c = t4 + it * 4;
    float m  = mu[b * C_ + c0 + c];
    float rs = rstd[b * C_ + c0 + c];
    tile[c][tn] = f2bf((xb[(size_t)c * N_ + tn] - m) * rs);
  }
  __syncthreads();
  u16* hTb = hT + ((size_t)b * N_ + n0) * C_ + c0;
#pragma unroll
  for (int it = 0; it < 16; ++it) {
    int n = t4 + it * 4;
    hTb[(size_t)n * C_ + tn] = tile[tn][n];
  }
}

// ============== 128x128 bf16 GEMM core (BK=64, dbuf, swizzled) ==============
// D[m][n] = sum_k A[m][k] * B[n][k], A/B row-major k-contiguous bf16.
// EPI: 0 bias[col]->bf16, 1 bias[row]->bf16,
//      2 P=exp2(acc*SCEXP)->bf16 (LDS-bounced full-line stores) + rowsums,
//      3 out = x + acc/aux[col]  (f32, non-atomic, full tile)
#define EPI_BCOL 0
#define EPI_BROW 1
#define EPI_EXP  2
#define EPI_PV   3

#define SCEXP 0.06376149809794171f  /* 512^-0.5 * log2(e) */

template<int EPI>
__global__ __launch_bounds__(256) void gemm128(
    const u16* __restrict__ A, const u16* __restrict__ B,
    const float* __restrict__ aux, float* __restrict__ dsum,
    void* __restrict__ Out, const float* __restrict__ xres,
    int klen, int lda, int ldb, int ldo,
    long sAz, long sBz, long sOz, long sAuxz, int koffZ)
{
  int z = blockIdx.z;
  const u16* Ab = A + (size_t)z * sAz;
  const u16* Bb = B + (size_t)z * sBz;
  int k0 = z * koffZ;
  int m0 = blockIdx.x * 128, n0 = blockIdx.y * 128;
  int t = threadIdx.x, w = t >> 6, l = t & 63;
  int wr = w >> 1, wc = w & 1;
  int l16 = l & 15, lg = l >> 4;

  __shared__ char smem[65536];            // 2 x (A 16KB + B 16KB)

  int srow = t >> 3;
  int scol = ((t & 7) << 4) ^ ((srow & 7) << 4);
  size_t ldaB = (size_t)lda * 2, ldbB = (size_t)ldb * 2;

  f32x4 acc[4][4] = {};
  int nsteps = klen >> 6;

#define STAGE(step, d) {                                                     \
    size_t kbyte = (size_t)(k0 + (step) * 64) * 2 + scol;                    \
    char* lb = smem + (d) * 32768;                                           \
    _Pragma("unroll")                                                        \
    for (int i = 0; i < 4; ++i) {                                            \
      int row = i * 32 + srow;                                               \
      gld16((const char*)Ab + (size_t)(m0 + row) * ldaB + kbyte,             \
            lb + (size_t)(i * 256 + t) * 16);                                \
      gld16((const char*)Bb + (size_t)(n0 + row) * ldbB + kbyte,             \
            lb + 16384 + (size_t)(i * 256 + t) * 16);                        \
    }                                                                        \
  }

  STAGE(0, 0);
  __syncthreads();
  int cur = 0;
  int sw = (l16 & 7) << 4;
  for (int s = 0; s < nsteps; ++s) {
    if (s + 1 < nsteps) STAGE(s + 1, cur ^ 1);
    const char* Al = smem + cur * 32768;
    const char* Bl = Al + 16384;
#pragma unroll
    for (int kc = 0; kc < 2; ++kc) {
      int cb = (kc * 64 + lg * 16) ^ sw;
      bf16x8 af[4], bf[4];
#pragma unroll
      for (int mf = 0; mf < 4; ++mf)
        af[mf] = *(const bf16x8*)(Al + (wr * 64 + mf * 16 + l16) * 128 + cb);
#pragma unroll
      for (int nf = 0; nf < 4; ++nf)
        bf[nf] = *(const bf16x8*)(Bl + (wc * 64 + nf * 16 + l16) * 128 + cb);
#pragma unroll
      for (int mf = 0; mf < 4; ++mf)
#pragma unroll
        for (int nf = 0; nf < 4; ++nf)
          acc[mf][nf] = __builtin_amdgcn_mfma_f32_16x16x32_bf16(af[mf], bf[nf], acc[mf][nf], 0, 0, 0);
    }
    __syncthreads();
    cur ^= 1;
  }
#undef STAGE

  // ---- epilogues ----
  if constexpr (EPI == EPI_BCOL || EPI == EPI_BROW) {
    u16* ob = (u16*)Out + (size_t)z * sOz;
    float bc[4];
    if constexpr (EPI == EPI_BCOL) {
#pragma unroll
      for (int nf = 0; nf < 4; ++nf) bc[nf] = aux[n0 + wc * 64 + nf * 16 + l16];
    }
#pragma unroll
    for (int mf = 0; mf < 4; ++mf) {
#pragma unroll
      for (int nf = 0; nf < 4; ++nf) {
        int col = n0 + wc * 64 + nf * 16 + l16;
#pragma unroll
        for (int r = 0; r < 4; ++r) {
          int row = m0 + wr * 64 + mf * 16 + lg * 4 + r;
          float v = acc[mf][nf][r] + (EPI == EPI_BCOL ? bc[nf] : aux[row]);
          ob[(size_t)row * ldo + col] = f2bf(v);
        }
      }
    }
  } else if constexpr (EPI == EPI_EXP) {
    // exp in-register, rowsum atomics, then LDS bounce -> full-line stores
    u16* ob = (u16*)Out + (size_t)z * sOz;
#pragma unroll
    for (int mf = 0; mf < 4; ++mf) {
      int rbase = wr * 64 + mf * 16 + lg * 4;
#pragma unroll
      for (int r = 0; r < 4; ++r) {
        int row = rbase + r;                         // tile-local 0..127
        int xorv = (row & 7) << 4;
        float rs = 0.f;
#pragma unroll
        for (int nf = 0; nf < 4; ++nf) {
          int colb = (wc * 64 + nf * 16 + l16) * 2;
          float p = __builtin_amdgcn_exp2f(acc[mf][nf][r] * SCEXP);
          u16 pb = f2bf(p);
          *(u16*)(smem + row * 256 + (colb ^ xorv)) = pb;
          rs += bf2f(pb);
        }
        rs += __shfl_xor(rs, 1); rs += __shfl_xor(rs, 2);
        rs += __shfl_xor(rs, 4); rs += __shfl_xor(rs, 8);
        if (l16 == 0) atomicAdd(&dsum[(size_t)z * sAuxz + m0 + row], rs);
      }
    }
    __syncthreads();
#pragma unroll
    for (int it = 0; it < 8; ++it) {
      int idx = it * 256 + t;
      int row = idx >> 4, g = idx & 15;
      uint4 val = *(uint4*)(smem + row * 256 + ((g * 16) ^ ((row & 7) << 4)));
      *(uint4*)(ob + (size_t)(m0 + row) * ldo + n0 + g * 8) = val;
    }
  } else {  // EPI_PV: out = x + acc / denom[col]
    float* ob = (float*)Out + (size_t)z * sOz;
    const float* xb = xres + (size_t)z * sOz;
    float rd[4];
#pragma unroll
    for (int nf = 0; nf < 4; ++nf)
      rd[nf] = 1.0f / aux[(size_t)z * sAuxz + n0 + wc * 64 + nf * 16 + l16];
#pragma unroll
    for (int mf = 0; mf < 4; ++mf) {
#pragma unroll
      for (int r = 0; r < 4; ++r) {
        int row = m0 + wr * 64 + mf * 16 + lg * 4 + r;
#pragma unroll
        for (int nf = 0; nf < 4; ++nf) {
          int col = n0 + wc * 64 + nf * 16 + l16;
          size_t o = (size_t)row * ldo + col;
          ob[o] = xb[o] + acc[mf][nf][r] * rd[nf];
        }
      }
    }
  }
}

// ================== round-1 fallback path (tiny ws) =========================
__global__ __launch_bounds__(256) void gemm_abT(
    const u16* __restrict__ A, const u16* __restrict__ Bm,
    const float* __restrict__ bias, u16* __restrict__ out,
    int ldo, int bias_is_row)
{
  int w = threadIdx.x >> 6, l = threadIdx.x & 63;
  int l16 = l & 15, lg = l >> 4;
  int m0 = blockIdx.x * 128 + (w >> 1) * 64;
  int n0 = blockIdx.y * 128 + (w & 1) * 64;
  f32x4 acc[4][4] = {};
  const u16* Ab = A  + (size_t)(m0 + l16) * 512 + lg * 8;
  const u16* Bb = Bm + (size_t)(n0 + l16) * 512 + lg * 8;
  for (int kc = 0; kc < 512; kc += 32) {
    bf16x8 af[4], bf[4];
#pragma unroll
    for (int i = 0; i < 4; ++i) af[i] = ld16g(Ab + (size_t)(i * 16) * 512 + kc);
#pragma unroll
    for (int j = 0; j < 4; ++j) bf[j] = ld16g(Bb + (size_t)(j * 16) * 512 + kc);
#pragma unroll
    for (int i = 0; i < 4; ++i)
#pragma unroll
      for (int j = 0; j < 4; ++j)
        acc[i][j] = __builtin_amdgcn_mfma_f32_16x16x32_bf16(af[i], bf[j], acc[i][j], 0, 0, 0);
  }
#pragma unroll
  for (int i = 0; i < 4; ++i) {
#pragma unroll
    for (int j = 0; j < 4; ++j) {
      int col = n0 + j * 16 + l16;
#pragma unroll
      for (int r = 0; r < 4; ++r) {
        int row = m0 + i * 16 + lg * 4 + r;
        float v = acc[i][j][r] + (bias_is_row ? bias[row] : bias[col]);
        out[(size_t)row * ldo + col] = f2bf(v);
      }
    }
  }
}

#define NQ 32
#define NKB 64
__global__ __launch_bounds__(512) void attn_kernel(
    const u16* __restrict__ qT, const u16* __restrict__ kT, const u16* __restrict__ vM,
    const float* __restrict__ x, float* __restrict__ out)
{
  int b = blockIdx.y;
  int nq0 = blockIdx.x * NQ;
  const u16* qTb = qT + (size_t)b * N_ * C_;
  const u16* kTb = kT + (size_t)b * N_ * C_;
  const u16* vb  = vM + (size_t)b * C_ * N_;
  const float* xb = x + (size_t)b * C_ * N_;
  float* ob = out + (size_t)b * C_ * N_;

  int tid = threadIdx.x;
  int w = tid >> 6, l = tid & 63, l16 = l & 15, lg = l >> 4;
  int nqf = w & 1, nkf = w >> 1;
  int c0 = w * 64;

  __shared__ u16 qlds[32][520];
  __shared__ u16 Plds[32][72];
  __shared__ float dpart[32][16];
  __shared__ float dfin[32];

  for (int idx = tid; idx < 32 * 64; idx += 512) {
    int row = idx >> 6, cg = idx & 63;
    *(uint4*)&qlds[row][cg * 8] = *(const uint4*)(qTb + (size_t)(nq0 + row) * C_ + cg * 8);
  }
  __syncthreads();

  f32x4 acc[2][4] = {};
  float dreg = 0.f;
  int drow = tid >> 4, dcol = (tid & 15) * 4;

  for (int nk0 = 0; nk0 < N_; nk0 += NKB) {
    f32x4 s = {0.f, 0.f, 0.f, 0.f};
    const u16* krow = kTb + (size_t)(nk0 + nkf * 16 + l16) * C_ + lg * 8;
#pragma unroll 4
    for (int kc = 0; kc < 16; ++kc) {
      U16B tq; tq.u = *(const uint4*)&qlds[nqf * 16 + l16][kc * 32 + lg * 8];
      bf16x8 kf = ld16g(krow + kc * 32);
      s = __builtin_amdgcn_mfma_f32_16x16x32_bf16(tq.v, kf, s, 0, 0, 0);
    }
    __syncthreads();
#pragma unroll
    for (int r = 0; r < 4; ++r) {
      float p = __builtin_amdgcn_exp2f(s[r] * SCEXP);
      Plds[nqf * 16 + lg * 4 + r][nkf * 16 + l16] = f2bf(p);
    }
    __syncthreads();
#pragma unroll
    for (int r = 0; r < 4; ++r) dreg += bf2f(Plds[drow][dcol + r]);
#pragma unroll
    for (int kk = 0; kk < 2; ++kk) {
      bf16x8 pf[2];
#pragma unroll
      for (int i = 0; i < 2; ++i) {
        U16B t2; t2.u = *(const uint4*)&Plds[i * 16 + l16][kk * 32 + lg * 8];
        pf[i] = t2.v;
      }
#pragma unroll
      for (int j = 0; j < 4; ++j) {
        bf16x8 vf = ld16g(vb + (size_t)(c0 + j * 16 + l16) * N_ + nk0 + kk * 32 + lg * 8);
#pragma unroll
        for (int i = 0; i < 2; ++i)
          acc[i][j] = __builtin_amdgcn_mfma_f32_16x16x32_bf16(pf[i], vf, acc[i][j], 0, 0, 0);
      }
    }
  }

  dpart[drow][tid & 15] = dreg;
  __syncthreads();
  if (tid < 32) {
    float s2 = 0.f;
#pragma unroll
    for (int g = 0; g < 16; ++g) s2 += dpart[tid][g];
    dfin[tid] = s2;
  }
  __syncthreads();

#pragma unroll
  for (int i = 0; i < 2; ++i) {
    float dinv[4];
#pragma unroll
    for (int r = 0; r < 4; ++r) dinv[r] = 1.f / dfin[i * 16 + lg * 4 + r];
    int nbase = nq0 + i * 16 + lg * 4;
#pragma unroll
    for (int j = 0; j < 4; ++j) {
      int c = c0 + j * 16 + l16;
      float4 xv = *(const float4*)(xb + (size_t)c * N_ + nbase);
      float4 o;
      o.x = xv.x + acc[i][j][0] * dinv[0];
      o.y = xv.y + acc[i][j][1] * dinv[1];
      o.z = xv.z + acc[i][j][2] * dinv[2];
      o.w = xv.w + acc[i][j][3] * dinv[3];
      *(float4*)(ob + (size_t)c * N_ + nbase) = o;
    }
  }
}

extern "C" void kernel_launch(void* const* d_in, const int* in_sizes, int n_in,
                              void* d_out, int out_size, void* d_ws, size_t ws_size,
                              hipStream_t stream) {
  (void)in_sizes; (void)n_in; (void)out_size;
  const float* x  = (const float*)d_in[0];
  const float* wq = (const float*)d_in[1];
  const float* bq = (const float*)d_in[2];
  const float* wk = (const float*)d_in[3];
  const float* bk = (const float*)d_in[4];
  const float* wv = (const float*)d_in[5];
  const float* bv = (const float*)d_in[6];
  float* out = (float*)d_out;
  char* ws = (char*)d_ws;

  const size_t NC = (size_t)N_ * C_;        // 2097152 elems
  const long  PB = (long)N_ * N_;           // 16777216 elems (33.55 MB bf16)

  const size_t NEED1 = 83951616;            // alias-P, per-batch
  const size_t NEED2 = 117506048;           // alias-P + 1 extra (2-batch pairs)
  const size_t NEED4 = 218169344;           // contiguous P[4] (full merge)

  if (ws_size >= NEED1) {
    u16*   wbf_q = (u16*)(ws);
    u16*   wbf_k = (u16*)(ws + 524288);
    u16*   wbf_v = (u16*)(ws + 1048576);
    float* mu    = (float*)(ws + 1572864);
    float* rstd  = (float*)(ws + 1581056);
    u16*   hT    = (u16*)(ws + 1589248);
    u16*   qT    = (u16*)(ws + 33554432);
    u16*   kT    = (u16*)(ws + 50331648);
    u16*   vM    = (u16*)(ws + 67108864);
    float* denomAll = (float*)(ws + 83886080);   // 4 x 4096 f32 = 64 KB
    u16*   Pext  = (u16*)(ws + 83951616);

    cvt_w<<<256, 256, 0, stream>>>(wq, wbf_q);
    cvt_w<<<256, 256, 0, stream>>>(wk, wbf_k);
    cvt_w<<<256, 256, 0, stream>>>(wv, wbf_v);
    inorm_stats<<<B_ * C_, 256, 0, stream>>>(x, mu, rstd);
    norm_transpose<<<dim3(N_ / 64, C_ / 64, B_), 256, 0, stream>>>(x, mu, rstd, hT);
    hipMemsetAsync(denomAll, 0, 4 * N_ * sizeof(float), stream);

    // projections (all batches, z = batch)
    gemm128<EPI_BCOL><<<dim3(32, 4, 4), 256, 0, stream>>>(
        hT, wbf_q, bq, nullptr, qT, nullptr, 512, 512, 512, 512, (long)NC, 0, (long)NC, 0, 0);
    gemm128<EPI_BCOL><<<dim3(32, 4, 4), 256, 0, stream>>>(
        hT, wbf_k, bk, nullptr, kT, nullptr, 512, 512, 512, 512, (long)NC, 0, (long)NC, 0, 0);
    gemm128<EPI_BROW><<<dim3(4, 32, 4), 256, 0, stream>>>(
        wbf_v, hT, bv, nullptr, vM, nullptr, 512, 512, 512, 4096, 0, (long)NC, (long)NC, 0, 0);

    if (ws_size >= NEED4) {
      // ---- full merge: P[4] contiguous at Pext ----
      gemm128<EPI_EXP><<<dim3(32, 32, 4), 256, 0, stream>>>(
          qT, kT, nullptr, denomAll, Pext, nullptr,
          512, 512, 512, 4096, (long)NC, (long)NC, PB, 4096, 0);
      gemm128<EPI_PV><<<dim3(4, 32, 4), 256, 0, stream>>>(
          vM, Pext, denomAll, nullptr, out, x,
          4096, 4096, 4096, 4096, (long)NC, PB, (long)NC, 4096, 0);
    } else if (ws_size >= NEED2) {
      // ---- 2-batch pairs: P0 aliases [0,33.55MB), P1 at Pext ----
      u16* P0 = (u16*)ws;
      long sP = (long)(83951616 / 2);              // elems between P0 and Pext
      for (int r = 0; r < 2; ++r) {
        int b0 = 2 * r;
        gemm128<EPI_EXP><<<dim3(32, 32, 1), 256, 0, stream>>>(
            qT + (size_t)b0 * NC, kT + (size_t)b0 * NC, nullptr,
            denomAll + (size_t)b0 * N_, P0, nullptr,
            512, 512, 512, 4096, 0, 0, 0, 0, 0);
        gemm128<EPI_EXP><<<dim3(32, 32, 1), 256, 0, stream>>>(
            qT + (size_t)(b0 + 1) * NC, kT + (size_t)(b0 + 1) * NC, nullptr,
            denomAll + (size_t)(b0 + 1) * N_, Pext, nullptr,
            512, 512, 512, 4096, 0, 0, 0, 0, 0);
        gemm128<EPI_PV><<<dim3(4, 32, 2), 256, 0, stream>>>(
            vM + (size_t)b0 * NC, P0, denomAll + (size_t)b0 * N_, nullptr,
            out + (size_t)b0 * NC, x + (size_t)b0 * NC,
            4096, 4096, 4096, 4096, (long)NC, sP, (long)NC, 4096, 0);
      }
    } else {
      // ---- per-batch: P aliases [0,33.55MB) ----
      u16* P0 = (u16*)ws;
      for (int b = 0; b < B_; ++b) {
        gemm128<EPI_EXP><<<dim3(32, 32, 1), 256, 0, stream>>>(
            qT + (size_t)b * NC, kT + (size_t)b * NC, nullptr,
            denomAll + (size_t)b * N_, P0, nullptr,
            512, 512, 512, 4096, 0, 0, 0, 0, 0);
        gemm128<EPI_PV><<<dim3(4, 32, 1), 256, 0, stream>>>(
            vM + (size_t)b * NC, P0, denomAll + (size_t)b * N_, nullptr,
            out + (size_t)b * NC, x + (size_t)b * NC,
            4096, 4096, 4096, 4096, 0, 0, 0, 4096, 0);
      }
    }
  } else {
    // ---- fallback: round-1 path (65.5 MB ws) ----
    u16*   wbf_q = (u16*)(ws);
    u16*   wbf_k = (u16*)(ws + 524288);
    u16*   wbf_v = (u16*)(ws + 1048576);
    float* mu    = (float*)(ws + 1572864);
    float* rstd  = (float*)(ws + 1581056);
    u16*   hT    = (u16*)(ws + 1589248);
    u16*   qT    = (u16*)(ws + 18366464);
    u16*   kT    = (u16*)(ws + 35143680);
    u16*   vM    = (u16*)(ws + 51920896);

    cvt_w<<<256, 256, 0, stream>>>(wq, wbf_q);
    cvt_w<<<256, 256, 0, stream>>>(wk, wbf_k);
    cvt_w<<<256, 256, 0, stream>>>(wv, wbf_v);
    inorm_stats<<<B_ * C_, 256, 0, stream>>>(x, mu, rstd);
    norm_transpose<<<dim3(N_ / 64, C_ / 64, B_), 256, 0, stream>>>(x, mu, rstd, hT);

    for (int b = 0; b < B_; ++b) {
      const u16* hTb = hT + (size_t)b * NC;
      u16* qTb = qT + (size_t)b * NC;
      u16* kTb = kT + (size_t)b * NC;
      u16* vMb = vM + (size_t)b * NC;
      gemm_abT<<<dim3(N_ / 128, C_ / 128), 256, 0, stream>>>(hTb, wbf_q, bq, qTb, C_, 0);
      gemm_abT<<<dim3(N_ / 128, C_ / 128), 256, 0, stream>>>(hTb, wbf_k, bk, kTb, C_, 0);
      gemm_abT<<<dim3(C_ / 128, N_ / 128), 256, 0, stream>>>(wbf_v, hTb, bv, vMb, N_, 1);
    }
    attn_kernel<<<dim3(N_ / NQ, B_), 512, 0, stream>>>(qT, kT, vM, x, out);
  }
}